// Round 8
// baseline (377.520 us; speedup 1.0000x reference)
//
#include <hip/hip_runtime.h>
#include <hip/hip_cooperative_groups.h>
namespace cg = cooperative_groups;

#define ND      10000
#define NDIS    10000
#define E_EDGES 400000
#define E4N     (E_EDGES / 4)
#define DIM     128
#define D2      256   // 2*DIM
#define H1      256   // d4/2
#define H2      128   // d4/4
#define EPSBN   1e-5f
#define GJ      8     // diseases per group in z1/z2
#define NGRP    (NDIS / GJ)   // 1250
#define NCOPY   32    // privatized histogram copies
#define ELLS    128   // ELL row stride (max degree bound; Poisson(40) -> safe)
#define GRID    256
#define BLK     512
#define GB      (GRID * BLK)  // 131072 threads
// zero region: NCOPY*(ND+NDIS) ints + 768 stat floats
#define ZERO_N4 ((NCOPY * (ND + NDIS) + 768) / 4)   // 160192 int4 items

struct Params {
    const float *h_drug, *Wg, *W1, *b_gcn, *b1, *gamma1, *beta1, *W2, *b2,
                *gamma2, *beta2, *W3, *b3;
    const int *src, *dst;
    float* out;
    int *cnts, *cntd, *rank, *ell_src, *cnt_dst;
    float *sum1, *sumsq1, *sum2, *sumsq2, *norm_out, *M1, *c1v, *aggn, *Z1, *Z2, *S;
};

// ======================= THE MEGA-KERNEL (cooperative) =======================
__global__ __launch_bounds__(BLK) void k_mega(Params p) {
    cg::grid_group grid = cg::this_grid();
    __shared__ float smem[6656];   // 26 KB, aliased per phase
    const int tid = threadIdx.x;
    const int gtid = blockIdx.x * BLK + tid;

    // ---------- P0: zero histograms/stats + M1/c1 precompute ----------
    {
        const int T0 = ZERO_N4, T1 = T0 + DIM * H1, T2 = T1 + H1;
        for (int id = gtid; id < T2; id += GB) {
            if (id < T0) {
                ((int4*)p.cnts)[id] = make_int4(0, 0, 0, 0);
            } else if (id < T1) {
                int m = id - T0, r = m >> 8, k = m & (H1 - 1);
                float acc = 0.f;
                #pragma unroll 8
                for (int c = 0; c < D2; ++c)
                    acc += p.Wg[r * D2 + c] * p.W1[(D2 + c) * H1 + k];
                p.M1[r * H1 + k] = acc;
            } else {
                int k = id - T1;
                float acc = p.b1[k];
                #pragma unroll 4
                for (int i = 0; i < D2; ++i)
                    acc += p.b_gcn[i] * (p.W1[i * H1 + k] + p.W1[(D2 + i) * H1 + k]);
                p.c1v[k] = acc;
            }
        }
    }
    grid.sync();
    // ---------- P1: degree counting (privatized) + dst rank ----------
    for (int e4 = gtid; e4 < E4N; e4 += GB) {
        int c = e4 & (NCOPY - 1);
        int4 sv = ((const int4*)p.src)[e4];
        int4 dv = ((const int4*)p.dst)[e4];
        atomicAdd(&p.cnts[c * ND + sv.x], 1);
        atomicAdd(&p.cnts[c * ND + sv.y], 1);
        atomicAdd(&p.cnts[c * ND + sv.z], 1);
        atomicAdd(&p.cnts[c * ND + sv.w], 1);
        int4 rv;
        rv.x = atomicAdd(&p.cntd[c * NDIS + dv.x], 1);
        rv.y = atomicAdd(&p.cntd[c * NDIS + dv.y], 1);
        rv.z = atomicAdd(&p.cntd[c * NDIS + dv.z], 1);
        rv.w = atomicAdd(&p.cntd[c * NDIS + dv.w], 1);
        ((int4*)p.rank)[e4] = rv;
    }
    grid.sync();
    // ---------- P2: reduce copies -> cnt_dst, copyoff (in place), norm_out ----------
    for (int d = gtid; d < NDIS; d += GB) {
        int s = 0;
        #pragma unroll
        for (int c = 0; c < NCOPY; ++c) {
            int v = p.cntd[c * NDIS + d];
            p.cntd[c * NDIS + d] = s;
            s += v;
        }
        p.cnt_dst[d] = s;
        int s2 = 0;
        #pragma unroll
        for (int c = 0; c < NCOPY; ++c) s2 += p.cnts[c * ND + d];
        p.norm_out[d] = rsqrtf(fmaxf((float)s2, 1.f));
    }
    grid.sync();
    // ---------- P3: ELL fill, atomic-free ----------
    for (int e4 = gtid; e4 < E4N; e4 += GB) {
        int c = e4 & (NCOPY - 1);
        int4 sv = ((const int4*)p.src)[e4];
        int4 dv = ((const int4*)p.dst)[e4];
        int4 rv = ((const int4*)p.rank)[e4];
        int ix = p.cntd[c * NDIS + dv.x] + rv.x;
        int iy = p.cntd[c * NDIS + dv.y] + rv.y;
        int iz = p.cntd[c * NDIS + dv.z] + rv.z;
        int iw = p.cntd[c * NDIS + dv.w] + rv.w;
        if (ix < ELLS) p.ell_src[(dv.x << 7) + ix] = sv.x;
        if (iy < ELLS) p.ell_src[(dv.y << 7) + iy] = sv.y;
        if (iz < ELLS) p.ell_src[(dv.z << 7) + iz] = sv.z;
        if (iw < ELLS) p.ell_src[(dv.w << 7) + iw] = sv.w;
    }
    grid.sync();
    // ---------- P4: aggregation, wave-per-disease, float4 ----------
    {
        int gw = gtid >> 6, lane = tid & 63, nw = GB >> 6;
        int half = lane >> 5, L = lane & 31;
        for (int j = gw; j < NDIS; j += nw) {
            int n = p.cnt_dst[j];
            int nn = n < ELLS ? n : ELLS;
            int beg = j << 7;
            float4 acc = make_float4(0.f, 0.f, 0.f, 0.f);
            float4 acc2 = make_float4(0.f, 0.f, 0.f, 0.f);
            int i = half;
            for (; i + 2 < nn; i += 4) {     // two independent chains per half-wave
                int s0 = p.ell_src[beg + i];
                int s1 = p.ell_src[beg + i + 2];
                float n0 = p.norm_out[s0], n1 = p.norm_out[s1];
                float4 v0 = *(const float4*)&p.h_drug[(size_t)s0 * DIM + L * 4];
                float4 v1 = *(const float4*)&p.h_drug[(size_t)s1 * DIM + L * 4];
                acc.x += n0 * v0.x; acc.y += n0 * v0.y; acc.z += n0 * v0.z; acc.w += n0 * v0.w;
                acc2.x += n1 * v1.x; acc2.y += n1 * v1.y; acc2.z += n1 * v1.z; acc2.w += n1 * v1.w;
            }
            for (; i < nn; i += 2) {
                int s0 = p.ell_src[beg + i];
                float n0 = p.norm_out[s0];
                float4 v0 = *(const float4*)&p.h_drug[(size_t)s0 * DIM + L * 4];
                acc.x += n0 * v0.x; acc.y += n0 * v0.y; acc.z += n0 * v0.z; acc.w += n0 * v0.w;
            }
            acc.x += acc2.x; acc.y += acc2.y; acc.z += acc2.z; acc.w += acc2.w;
            acc.x += __shfl_down(acc.x, 32, 64);
            acc.y += __shfl_down(acc.y, 32, 64);
            acc.z += __shfl_down(acc.z, 32, 64);
            acc.w += __shfl_down(acc.w, 32, 64);
            if (half == 0) {
                float ni = rsqrtf(fmaxf((float)n, 1.f));
                acc.x *= ni; acc.y *= ni; acc.z *= ni; acc.w *= ni;
                *(float4*)&p.aggn[(size_t)j * DIM + L * 4] = acc;
            }
        }
    }
    grid.sync();
    // ---------- P5: Z1 = aggn @ M1 + c1 ; weighted BN1 stats ----------
    {
        float* sA = smem;            // [GJ][DIM]      4 KB
        float* sP = smem + 1024;     // [GJ][2][H1]   16 KB
        int k = tid & (H1 - 1);
        int isplit = tid >> 8;
        float m[64];
        #pragma unroll
        for (int r = 0; r < 64; ++r)
            m[r] = p.M1[(isplit * 64 + r) * H1 + k];
        float c1k = p.c1v[k];
        float psum = 0.f, psq = 0.f;
        for (int grp = blockIdx.x; grp < NGRP; grp += GRID) {
            int jb = grp * GJ;
            for (int x = tid; x < GJ * DIM / 4; x += BLK)
                ((float4*)sA)[x] = ((const float4*)(p.aggn + (size_t)jb * DIM))[x];
            __syncthreads();
            #pragma unroll
            for (int g = 0; g < GJ; ++g) {
                const float4* a4 = (const float4*)(sA + g * DIM) + isplit * 16;
                float pp = 0.f;
                #pragma unroll
                for (int ii = 0; ii < 16; ++ii) {
                    float4 v = a4[ii];   // wave-uniform address -> LDS broadcast
                    pp += v.x * m[4*ii] + v.y * m[4*ii+1] + v.z * m[4*ii+2] + v.w * m[4*ii+3];
                }
                sP[(g * 2 + isplit) * H1 + k] = pp;
            }
            __syncthreads();
            if (tid < H1) {
                #pragma unroll
                for (int g = 0; g < GJ; ++g) {
                    float z = sP[(g * 2 + 0) * H1 + k] + sP[(g * 2 + 1) * H1 + k] + c1k;
                    p.Z1[(size_t)(jb + g) * H1 + k] = z;
                    float w = (float)p.cnt_dst[jb + g];
                    psum += w * z;
                    psq  += w * z * z;
                }
            }
            __syncthreads();
        }
        if (tid < H1) {
            atomicAdd(&p.sum1[k], psum);
            atomicAdd(&p.sumsq1[k], psq);
        }
    }
    grid.sync();
    // ---------- P6: Z2 = relu(bn1(Z1)) @ W2 + b2 ; weighted BN2 stats ----------
    {
        float* sX  = smem;           // [GJ][H1]       8 KB
        float* sP2 = smem + 2048;    // [GJ][4][H2]   16 KB
        float* sc1 = smem + 6144;    // [H1]           1 KB
        float* sh1 = smem + 6400;    // [H1]           1 KB
        int k = tid & (H2 - 1);
        int csplit = tid >> 7;
        float w2r[64];
        #pragma unroll
        for (int r = 0; r < 64; ++r)
            w2r[r] = p.W2[(csplit * 64 + r) * H2 + k];
        if (tid < H1) {   // inline BN1 finalize
            float mn = p.sum1[tid] * (1.f / E_EDGES);
            float vv = p.sumsq1[tid] * (1.f / E_EDGES) - mn * mn;
            float s = rsqrtf(vv + EPSBN) * p.gamma1[tid];
            sc1[tid] = s;
            sh1[tid] = p.beta1[tid] - mn * s;
        }
        float b2k = p.b2[k];
        float psum = 0.f, psq = 0.f;
        __syncthreads();
        for (int grp = blockIdx.x; grp < NGRP; grp += GRID) {
            int jb = grp * GJ;
            for (int x = tid; x < GJ * H1 / 4; x += BLK) {
                float4 v = ((const float4*)(p.Z1 + (size_t)jb * H1))[x];
                int c = (x * 4) & (H1 - 1);
                v.x = fmaxf(v.x * sc1[c]     + sh1[c],     0.f);
                v.y = fmaxf(v.y * sc1[c + 1] + sh1[c + 1], 0.f);
                v.z = fmaxf(v.z * sc1[c + 2] + sh1[c + 2], 0.f);
                v.w = fmaxf(v.w * sc1[c + 3] + sh1[c + 3], 0.f);
                ((float4*)sX)[x] = v;
            }
            __syncthreads();
            #pragma unroll
            for (int g = 0; g < GJ; ++g) {
                const float4* x4 = (const float4*)(sX + g * H1) + csplit * 16;
                float pp = 0.f;
                #pragma unroll
                for (int ii = 0; ii < 16; ++ii) {
                    float4 v = x4[ii];   // wave-uniform address -> LDS broadcast
                    pp += v.x * w2r[4*ii] + v.y * w2r[4*ii+1] + v.z * w2r[4*ii+2] + v.w * w2r[4*ii+3];
                }
                sP2[(g * 4 + csplit) * H2 + k] = pp;
            }
            __syncthreads();
            if (tid < H2) {
                #pragma unroll
                for (int g = 0; g < GJ; ++g) {
                    float z = sP2[(g*4+0)*H2+k] + sP2[(g*4+1)*H2+k]
                            + sP2[(g*4+2)*H2+k] + sP2[(g*4+3)*H2+k] + b2k;
                    p.Z2[(size_t)(jb + g) * H2 + k] = z;
                    float w = (float)p.cnt_dst[jb + g];
                    psum += w * z;
                    psq  += w * z * z;
                }
            }
            __syncthreads();
        }
        if (tid < H2) {
            atomicAdd(&p.sum2[k], psum);
            atomicAdd(&p.sumsq2[k], psq);
        }
    }
    grid.sync();
    // ---------- P7: scores (inline BN2) ----------
    {
        int gw = gtid >> 6, lane = tid & 63, nw = GB >> 6;
        for (int j = gw; j < NDIS; j += nw) {
            float acc = 0.f;
            #pragma unroll
            for (int k = lane; k < H2; k += 64) {
                float m = p.sum2[k] * (1.f / E_EDGES);
                float v = p.sumsq2[k] * (1.f / E_EDGES) - m * m;
                float s = rsqrtf(v + EPSBN) * p.gamma2[k];
                float sh = p.beta2[k] - m * s;
                float x = fmaxf(p.Z2[(size_t)j * H2 + k] * s + sh, 0.f);
                acc += x * p.W3[k];
            }
            for (int off = 32; off > 0; off >>= 1)
                acc += __shfl_down(acc, off, 64);
            if (lane == 0) p.S[j] = 1.f / (1.f + expf(-(acc + p.b3[0])));
        }
    }
    grid.sync();
    // ---------- P8: out[e] = S[dst[e]] ----------
    for (int e4 = gtid; e4 < E4N; e4 += GB) {
        int4 d = ((const int4*)p.dst)[e4];
        float4 o;
        o.x = p.S[d.x]; o.y = p.S[d.y]; o.z = p.S[d.z]; o.w = p.S[d.w];
        ((float4*)p.out)[e4] = o;
    }
}

extern "C" void kernel_launch(void* const* d_in, const int* in_sizes, int n_in,
                              void* d_out, int out_size, void* d_ws, size_t ws_size,
                              hipStream_t stream) {
    const float* h_drug    = (const float*)d_in[0];
    // d_in[1] = d_disease: unused (diseases only receive; drugs' GCN output is b_gcn)
    const float* W_gcn     = (const float*)d_in[2];
    const float* b_gcn     = (const float*)d_in[3];
    const float* W1        = (const float*)d_in[4];
    const float* b1        = (const float*)d_in[5];
    const float* gamma1    = (const float*)d_in[6];
    const float* beta1     = (const float*)d_in[7];
    const float* W2        = (const float*)d_in[8];
    const float* b2        = (const float*)d_in[9];
    const float* gamma2    = (const float*)d_in[10];
    const float* beta2     = (const float*)d_in[11];
    const float* W3        = (const float*)d_in[12];
    const float* b3        = (const float*)d_in[13];
    const int*   src       = (const int*)d_in[14];
    const int*   dst       = (const int*)d_in[15];
    float* out = (float*)d_out;

    char* ws = (char*)d_ws;
    int*   cnts    = (int*)ws;                        // 32*ND
    int*   cntd    = cnts + NCOPY * ND;               // 32*NDIS (becomes copyoff)
    float* sum1    = (float*)(cntd + NCOPY * NDIS);   // 256
    float* sumsq1  = sum1 + H1;                       // 256
    float* sum2    = sumsq1 + H1;                     // 128
    float* sumsq2  = sum2 + H2;                       // 128
    float* zero_end = sumsq2 + H2;

    int*   cnt_dst  = (int*)zero_end;                 // NDIS
    float* norm_out = (float*)(cnt_dst + NDIS);       // ND
    int*   rank     = (int*)(norm_out + ND);          // E
    int*   ell_src  = rank + E_EDGES;                 // NDIS*ELLS
    float* M1       = (float*)(ell_src + NDIS * ELLS);// 128*256
    float* c1v      = M1 + DIM * H1;                  // 256
    float* aggn     = c1v + H1;                       // NDIS*128
    float* Z1       = aggn + (size_t)NDIS * DIM;      // NDIS*256
    float* Z2       = Z1 + (size_t)NDIS * H1;         // NDIS*128
    float* S        = Z2 + (size_t)NDIS * H2;         // NDIS

    Params prm;
    prm.h_drug = h_drug; prm.Wg = W_gcn; prm.W1 = W1; prm.b_gcn = b_gcn; prm.b1 = b1;
    prm.gamma1 = gamma1; prm.beta1 = beta1; prm.W2 = W2; prm.b2 = b2;
    prm.gamma2 = gamma2; prm.beta2 = beta2; prm.W3 = W3; prm.b3 = b3;
    prm.src = src; prm.dst = dst; prm.out = out;
    prm.cnts = cnts; prm.cntd = cntd; prm.rank = rank; prm.ell_src = ell_src;
    prm.cnt_dst = cnt_dst;
    prm.sum1 = sum1; prm.sumsq1 = sumsq1; prm.sum2 = sum2; prm.sumsq2 = sumsq2;
    prm.norm_out = norm_out; prm.M1 = M1; prm.c1v = c1v; prm.aggn = aggn;
    prm.Z1 = Z1; prm.Z2 = Z2; prm.S = S;

    void* args[] = { &prm };
    hipLaunchCooperativeKernel((const void*)k_mega, dim3(GRID), dim3(BLK),
                               args, 0, stream);
}

// Round 9
// 144.359 us; speedup vs baseline: 2.6152x; 2.6152x over previous
//
#include <hip/hip_runtime.h>

#define ND      10000
#define NDIS    10000
#define E_EDGES 400000
#define DIM     128
#define D2      256   // 2*DIM
#define H1      256   // d4/2
#define H2      128   // d4/4
#define EPSBN   1e-5f
#define GJ      8     // diseases per group in z1/z2
#define NGRP    (NDIS / GJ)   // 1250
#define WSGRID  512
#define NCOPY   32    // privatized histogram copies
#define ELLS    128   // ELL row stride (max degree bound; Poisson(40) -> safe)
// zero region: NCOPY*(ND+NDIS) ints + 768 stat floats
#define ZERO_N4 ((NCOPY * (ND + NDIS) + 768) / 4)
#define ZBLK    ((ZERO_N4 + 255) / 256)

// ---------------- fused: zero histograms/stats  +  M1/c1 precompute ----------------
__global__ void k_pre(int4* __restrict__ zp,
                      const float* __restrict__ Wg, const float* __restrict__ W1,
                      const float* __restrict__ b_gcn, const float* __restrict__ b1,
                      float* __restrict__ M1, float* __restrict__ c1) {
    int b = blockIdx.x;
    int t = threadIdx.x;
    if (b < ZBLK) {
        int i = b * 256 + t;
        if (i < ZERO_N4) zp[i] = make_int4(0, 0, 0, 0);
        return;
    }
    int r = b - ZBLK;          // 0..128
    if (r < DIM) {             // M1[r][t] = sum_c Wg[r][c] * W1[256+c][t]
        float acc = 0.f;
        #pragma unroll 8
        for (int c = 0; c < D2; ++c)
            acc += Wg[r * D2 + c] * W1[(D2 + c) * H1 + t];
        M1[r * H1 + t] = acc;
    } else {                   // c1[t]
        float acc = b1[t];
        #pragma unroll 4
        for (int i = 0; i < D2; ++i)
            acc += b_gcn[i] * (W1[i * H1 + t] + W1[(D2 + i) * H1 + t]);
        c1[t] = acc;
    }
}

// ---------------- degree counting, 32-way privatized; dst-atomic returns edge rank -------
__global__ void k_degrees(const int* __restrict__ src, const int* __restrict__ dst,
                          int* __restrict__ cnts, int* __restrict__ cntd,
                          int* __restrict__ rank) {
    int e4 = blockIdx.x * blockDim.x + threadIdx.x;
    if (e4 >= E_EDGES / 4) return;
    int c = blockIdx.x & (NCOPY - 1);
    int4 sv = ((const int4*)src)[e4];
    int4 dv = ((const int4*)dst)[e4];
    atomicAdd(&cnts[c * ND + sv.x], 1);
    atomicAdd(&cnts[c * ND + sv.y], 1);
    atomicAdd(&cnts[c * ND + sv.z], 1);
    atomicAdd(&cnts[c * ND + sv.w], 1);
    int4 rv;
    rv.x = atomicAdd(&cntd[c * NDIS + dv.x], 1);
    rv.y = atomicAdd(&cntd[c * NDIS + dv.y], 1);
    rv.z = atomicAdd(&cntd[c * NDIS + dv.z], 1);
    rv.w = atomicAdd(&cntd[c * NDIS + dv.w], 1);
    ((int4*)rank)[e4] = rv;
}

// ------- reduce copies: totals, in-place per-copy exclusive prefix, norm_out -------------
__global__ void k_red(int* __restrict__ cnts, int* __restrict__ cntd,
                      int* __restrict__ cnt_dst, float* __restrict__ norm_out) {
    int d = blockIdx.x * blockDim.x + threadIdx.x;
    if (d >= NDIS) return;
    int s = 0;
    #pragma unroll
    for (int c = 0; c < NCOPY; ++c) {
        int v = cntd[c * NDIS + d];
        cntd[c * NDIS + d] = s;       // overwrite with exclusive prefix (copyoff)
        s += v;
    }
    cnt_dst[d] = s;
    int s2 = 0;
    #pragma unroll
    for (int c = 0; c < NCOPY; ++c) s2 += cnts[c * ND + d];
    norm_out[d] = rsqrtf(fmaxf((float)s2, 1.f));
}

// ---------------- ELL fill, atomic-free: pos = (d<<7) + copyoff[c][d] + rank[e] ----------
__global__ void k_fill(const int* __restrict__ src, const int* __restrict__ dst,
                       const int* __restrict__ rank,
                       const int* __restrict__ copyoff, int* __restrict__ ell_src) {
    int e4 = blockIdx.x * blockDim.x + threadIdx.x;
    if (e4 >= E_EDGES / 4) return;
    int c = blockIdx.x & (NCOPY - 1);          // must match k_degrees' mapping
    int4 sv = ((const int4*)src)[e4];
    int4 dv = ((const int4*)dst)[e4];
    int4 rv = ((const int4*)rank)[e4];
    int ix = copyoff[c * NDIS + dv.x] + rv.x;
    int iy = copyoff[c * NDIS + dv.y] + rv.y;
    int iz = copyoff[c * NDIS + dv.z] + rv.z;
    int iw = copyoff[c * NDIS + dv.w] + rv.w;
    if (ix < ELLS) ell_src[(dv.x << 7) + ix] = sv.x;
    if (iy < ELLS) ell_src[(dv.y << 7) + iy] = sv.y;
    if (iz < ELLS) ell_src[(dv.z << 7) + iz] = sv.z;
    if (iw < ELLS) ell_src[(dv.w << 7) + iw] = sv.w;
}

// ------- aggregation: wave-per-disease, half-wave float4 row loads (from mega P4) --------
__global__ void k_agg(const int* __restrict__ ell_src,
                      const int* __restrict__ cnt_dst, const float* __restrict__ norm_out,
                      const float* __restrict__ h_drug, float* __restrict__ aggn) {
    int j = (blockIdx.x * blockDim.x + threadIdx.x) >> 6;
    if (j >= NDIS) return;
    int lane = threadIdx.x & 63;
    int half = lane >> 5, L = lane & 31;
    int n = cnt_dst[j];
    int nn = n < ELLS ? n : ELLS;
    int beg = j << 7;
    float4 acc = make_float4(0.f, 0.f, 0.f, 0.f);
    float4 acc2 = make_float4(0.f, 0.f, 0.f, 0.f);
    int i = half;
    for (; i + 2 < nn; i += 4) {     // two independent chains per half-wave
        int s0 = ell_src[beg + i];
        int s1 = ell_src[beg + i + 2];
        float n0 = norm_out[s0], n1 = norm_out[s1];
        float4 v0 = *(const float4*)&h_drug[(size_t)s0 * DIM + L * 4];
        float4 v1 = *(const float4*)&h_drug[(size_t)s1 * DIM + L * 4];
        acc.x += n0 * v0.x; acc.y += n0 * v0.y; acc.z += n0 * v0.z; acc.w += n0 * v0.w;
        acc2.x += n1 * v1.x; acc2.y += n1 * v1.y; acc2.z += n1 * v1.z; acc2.w += n1 * v1.w;
    }
    for (; i < nn; i += 2) {
        int s0 = ell_src[beg + i];
        float n0 = norm_out[s0];
        float4 v0 = *(const float4*)&h_drug[(size_t)s0 * DIM + L * 4];
        acc.x += n0 * v0.x; acc.y += n0 * v0.y; acc.z += n0 * v0.z; acc.w += n0 * v0.w;
    }
    acc.x += acc2.x; acc.y += acc2.y; acc.z += acc2.z; acc.w += acc2.w;
    acc.x += __shfl_down(acc.x, 32, 64);
    acc.y += __shfl_down(acc.y, 32, 64);
    acc.z += __shfl_down(acc.z, 32, 64);
    acc.w += __shfl_down(acc.w, 32, 64);
    if (half == 0) {
        float ni = rsqrtf(fmaxf((float)n, 1.f));
        acc.x *= ni; acc.y *= ni; acc.z *= ni; acc.w *= ni;
        *(float4*)&aggn[(size_t)j * DIM + L * 4] = acc;
    }
}

// ------- Z1 = aggn @ M1 + c1 ; weighted BN1 stats.  M1 column-slice in registers ---------
__global__ __launch_bounds__(512) void k_z1w(
        const float* __restrict__ aggn, const int* __restrict__ cnt_dst,
        const float* __restrict__ M1, const float* __restrict__ c1,
        float* __restrict__ Z1, float* __restrict__ sum1, float* __restrict__ sumsq1) {
    __shared__ float sA[GJ][DIM];          // 4 KB
    __shared__ float sP[GJ][2][H1];        // 16 KB
    int tid = threadIdx.x;
    int k = tid & (H1 - 1);
    int isplit = tid >> 8;
    float m[64];
    #pragma unroll
    for (int r = 0; r < 64; ++r)
        m[r] = M1[(isplit * 64 + r) * H1 + k];
    float c1k = c1[k];
    float psum = 0.f, psq = 0.f;
    for (int grp = blockIdx.x; grp < NGRP; grp += gridDim.x) {
        int jb = grp * GJ;
        for (int x = tid; x < GJ * DIM / 4; x += 512)
            ((float4*)sA)[x] = ((const float4*)(aggn + (size_t)jb * DIM))[x];
        __syncthreads();
        #pragma unroll
        for (int g = 0; g < GJ; ++g) {
            const float4* a4 = (const float4*)sA[g] + isplit * 16;
            float p = 0.f;
            #pragma unroll
            for (int ii = 0; ii < 16; ++ii) {
                float4 v = a4[ii];   // wave-uniform address -> LDS broadcast
                p += v.x * m[4*ii] + v.y * m[4*ii+1] + v.z * m[4*ii+2] + v.w * m[4*ii+3];
            }
            sP[g][isplit][k] = p;
        }
        __syncthreads();
        if (tid < H1) {
            #pragma unroll
            for (int g = 0; g < GJ; ++g) {
                float z = sP[g][0][k] + sP[g][1][k] + c1k;
                Z1[(size_t)(jb + g) * H1 + k] = z;
                float w = (float)cnt_dst[jb + g];
                psum += w * z;
                psq  += w * z * z;
            }
        }
        __syncthreads();
    }
    if (tid < H1) {
        atomicAdd(&sum1[k], psum);
        atomicAdd(&sumsq1[k], psq);
    }
}

// ------- Z2 = relu(bn1(Z1)) @ W2 + b2 ; BN2 stats.  W2 column-slice in registers ---------
__global__ __launch_bounds__(512) void k_z2w(
        const float* __restrict__ Z1, const int* __restrict__ cnt_dst,
        const float* __restrict__ sum1, const float* __restrict__ sumsq1,
        const float* __restrict__ gamma1, const float* __restrict__ beta1,
        const float* __restrict__ W2, const float* __restrict__ b2,
        float* __restrict__ Z2, float* __restrict__ sum2, float* __restrict__ sumsq2) {
    __shared__ float sX[GJ][H1];           // 8 KB
    __shared__ float sP[GJ][4][H2];        // 16 KB
    __shared__ float sc1[H1], sh1[H1];     // 2 KB
    int tid = threadIdx.x;
    int k = tid & (H2 - 1);
    int csplit = tid >> 7;
    float w2r[64];
    #pragma unroll
    for (int r = 0; r < 64; ++r)
        w2r[r] = W2[(csplit * 64 + r) * H2 + k];
    if (tid < H1) {   // inline BN1 finalize
        float mn = sum1[tid] * (1.f / E_EDGES);
        float vv = sumsq1[tid] * (1.f / E_EDGES) - mn * mn;
        float s = rsqrtf(vv + EPSBN) * gamma1[tid];
        sc1[tid] = s;
        sh1[tid] = beta1[tid] - mn * s;
    }
    float b2k = b2[k];
    float psum = 0.f, psq = 0.f;
    __syncthreads();
    for (int grp = blockIdx.x; grp < NGRP; grp += gridDim.x) {
        int jb = grp * GJ;
        for (int x = tid; x < GJ * H1 / 4; x += 512) {
            float4 v = ((const float4*)(Z1 + (size_t)jb * H1))[x];
            int c = (x * 4) & (H1 - 1);
            v.x = fmaxf(v.x * sc1[c]     + sh1[c],     0.f);
            v.y = fmaxf(v.y * sc1[c + 1] + sh1[c + 1], 0.f);
            v.z = fmaxf(v.z * sc1[c + 2] + sh1[c + 2], 0.f);
            v.w = fmaxf(v.w * sc1[c + 3] + sh1[c + 3], 0.f);
            ((float4*)sX)[x] = v;
        }
        __syncthreads();
        #pragma unroll
        for (int g = 0; g < GJ; ++g) {
            const float4* x4 = (const float4*)sX[g] + csplit * 16;
            float p = 0.f;
            #pragma unroll
            for (int ii = 0; ii < 16; ++ii) {
                float4 v = x4[ii];   // wave-uniform address -> LDS broadcast
                p += v.x * w2r[4*ii] + v.y * w2r[4*ii+1] + v.z * w2r[4*ii+2] + v.w * w2r[4*ii+3];
            }
            sP[g][csplit][k] = p;
        }
        __syncthreads();
        if (tid < H2) {
            #pragma unroll
            for (int g = 0; g < GJ; ++g) {
                float z = sP[g][0][k] + sP[g][1][k] + sP[g][2][k] + sP[g][3][k] + b2k;
                Z2[(size_t)(jb + g) * H2 + k] = z;
                float w = (float)cnt_dst[jb + g];
                psum += w * z;
                psq  += w * z * z;
            }
        }
        __syncthreads();
    }
    if (tid < H2) {
        atomicAdd(&sum2[k], psum);
        atomicAdd(&sumsq2[k], psq);
    }
}

// ---------------- S[j] = sigmoid( relu(bn2(Z2[j])) @ W3 + b3 )  (inline BN2) -------------
__global__ void k_score(const float* __restrict__ Z2,
                        const float* __restrict__ sum2, const float* __restrict__ sumsq2,
                        const float* __restrict__ gamma2, const float* __restrict__ beta2,
                        const float* __restrict__ W3, const float* __restrict__ b3,
                        float* __restrict__ S) {
    int lane = threadIdx.x & 63;
    int j = blockIdx.x * (blockDim.x >> 6) + (threadIdx.x >> 6);
    if (j >= NDIS) return;
    float acc = 0.f;
    #pragma unroll
    for (int k = lane; k < H2; k += 64) {
        float m = sum2[k] * (1.f / E_EDGES);
        float v = sumsq2[k] * (1.f / E_EDGES) - m * m;
        float s = rsqrtf(v + EPSBN) * gamma2[k];
        float sh = beta2[k] - m * s;
        float x = fmaxf(Z2[(size_t)j * H2 + k] * s + sh, 0.f);
        acc += x * W3[k];
    }
    for (int off = 32; off > 0; off >>= 1)
        acc += __shfl_down(acc, off, 64);
    if (lane == 0) S[j] = 1.f / (1.f + expf(-(acc + b3[0])));
}

// ---------------- out[e] = S[dst[e]]  (int4/float4) ----------------
__global__ void k_out(const int* __restrict__ dst, const float* __restrict__ S,
                      float* __restrict__ out) {
    int e4 = blockIdx.x * blockDim.x + threadIdx.x;
    if (e4 < E_EDGES / 4) {
        int4 d = ((const int4*)dst)[e4];
        float4 o;
        o.x = S[d.x]; o.y = S[d.y]; o.z = S[d.z]; o.w = S[d.w];
        ((float4*)out)[e4] = o;
    }
}

extern "C" void kernel_launch(void* const* d_in, const int* in_sizes, int n_in,
                              void* d_out, int out_size, void* d_ws, size_t ws_size,
                              hipStream_t stream) {
    const float* h_drug    = (const float*)d_in[0];
    // d_in[1] = d_disease: unused (diseases only receive; drugs' GCN output is b_gcn)
    const float* W_gcn     = (const float*)d_in[2];
    const float* b_gcn     = (const float*)d_in[3];
    const float* W1        = (const float*)d_in[4];
    const float* b1        = (const float*)d_in[5];
    const float* gamma1    = (const float*)d_in[6];
    const float* beta1     = (const float*)d_in[7];
    const float* W2        = (const float*)d_in[8];
    const float* b2        = (const float*)d_in[9];
    const float* gamma2    = (const float*)d_in[10];
    const float* beta2     = (const float*)d_in[11];
    const float* W3        = (const float*)d_in[12];
    const float* b3        = (const float*)d_in[13];
    const int*   src       = (const int*)d_in[14];
    const int*   dst       = (const int*)d_in[15];
    float* out = (float*)d_out;

    // ---- workspace: zero-region first (k_pre), then uninitialized scratch ----
    char* ws = (char*)d_ws;
    int*   cnts    = (int*)ws;                       // 32*ND
    int*   cntd    = cnts + NCOPY * ND;              // 32*NDIS (becomes copyoff)
    float* sum1    = (float*)(cntd + NCOPY * NDIS);  // 256
    float* sumsq1  = sum1 + H1;                      // 256
    float* sum2    = sumsq1 + H1;                    // 128
    float* sumsq2  = sum2 + H2;                      // 128
    float* zero_end = sumsq2 + H2;

    int*   cnt_dst  = (int*)zero_end;                // NDIS
    float* norm_out = (float*)(cnt_dst + NDIS);      // ND
    int*   rank     = (int*)(norm_out + ND);         // E
    int*   ell_src  = rank + E_EDGES;                // NDIS*ELLS
    float* M1       = (float*)(ell_src + NDIS * ELLS); // 128*256
    float* c1v      = M1 + DIM * H1;                 // 256
    float* aggn     = c1v + H1;                      // NDIS*128
    float* Z1       = aggn + (size_t)NDIS * DIM;     // NDIS*256
    float* Z2       = Z1 + (size_t)NDIS * H1;        // NDIS*128
    float* S        = Z2 + (size_t)NDIS * H2;        // NDIS

    k_pre<<<ZBLK + DIM + 1, 256, 0, stream>>>((int4*)d_ws, W_gcn, W1, b_gcn, b1, M1, c1v);
    k_degrees<<<(E_EDGES / 4 + 255) / 256, 256, 0, stream>>>(src, dst, cnts, cntd, rank);
    k_red<<<(NDIS + 255) / 256, 256, 0, stream>>>(cnts, cntd, cnt_dst, norm_out);
    k_fill<<<(E_EDGES / 4 + 255) / 256, 256, 0, stream>>>(src, dst, rank, cntd, ell_src);
    k_agg<<<(NDIS * 64 + 255) / 256, 256, 0, stream>>>(ell_src, cnt_dst, norm_out, h_drug, aggn);
    k_z1w<<<WSGRID, 512, 0, stream>>>(aggn, cnt_dst, M1, c1v, Z1, sum1, sumsq1);
    k_z2w<<<WSGRID, 512, 0, stream>>>(Z1, cnt_dst, sum1, sumsq1, gamma1, beta1,
                                      W2, b2, Z2, sum2, sumsq2);
    k_score<<<(NDIS + 3) / 4, 256, 0, stream>>>(Z2, sum2, sumsq2, gamma2, beta2, W3, b3, S);
    k_out<<<(E_EDGES / 4 + 255) / 256, 256, 0, stream>>>(dst, S, out);
}

// Round 10
// 141.732 us; speedup vs baseline: 2.6636x; 1.0185x over previous
//
#include <hip/hip_runtime.h>

#define ND      10000
#define NDIS    10000
#define E_EDGES 400000
#define DIM     128
#define D2      256   // 2*DIM
#define H1      256   // d4/2
#define H2      128   // d4/4
#define EPSBN   1e-5f
#define GJ      8     // diseases per group in aggz1/z2 (= waves per block)
#define NGRP    (NDIS / GJ)   // 1250
#define WSGRID  512
#define NCOPY   32    // privatized histogram copies
#define ELLS    128   // ELL row stride (max degree bound; Poisson(40) -> safe)
// zero region: NCOPY*(ND+NDIS) ints + 768 stat floats
#define ZERO_N4 ((NCOPY * (ND + NDIS) + 768) / 4)
#define ZBLK    ((ZERO_N4 + 255) / 256)

// ---------------- fused: zero histograms/stats  +  M1/c1 precompute ----------------
__global__ void k_pre(int4* __restrict__ zp,
                      const float* __restrict__ Wg, const float* __restrict__ W1,
                      const float* __restrict__ b_gcn, const float* __restrict__ b1,
                      float* __restrict__ M1, float* __restrict__ c1) {
    int b = blockIdx.x;
    int t = threadIdx.x;
    if (b < ZBLK) {
        int i = b * 256 + t;
        if (i < ZERO_N4) zp[i] = make_int4(0, 0, 0, 0);
        return;
    }
    int r = b - ZBLK;          // 0..128
    if (r < DIM) {             // M1[r][t] = sum_c Wg[r][c] * W1[256+c][t]
        float acc = 0.f;
        #pragma unroll 8
        for (int c = 0; c < D2; ++c)
            acc += Wg[r * D2 + c] * W1[(D2 + c) * H1 + t];
        M1[r * H1 + t] = acc;
    } else {                   // c1[t]
        float acc = b1[t];
        #pragma unroll 4
        for (int i = 0; i < D2; ++i)
            acc += b_gcn[i] * (W1[i * H1 + t] + W1[(D2 + i) * H1 + t]);
        c1[t] = acc;
    }
}

// ---------------- degree counting, 32-way privatized; dst-atomic returns edge rank -------
__global__ void k_degrees(const int* __restrict__ src, const int* __restrict__ dst,
                          int* __restrict__ cnts, int* __restrict__ cntd,
                          int* __restrict__ rank) {
    int e4 = blockIdx.x * blockDim.x + threadIdx.x;
    if (e4 >= E_EDGES / 4) return;
    int c = blockIdx.x & (NCOPY - 1);
    int4 sv = ((const int4*)src)[e4];
    int4 dv = ((const int4*)dst)[e4];
    atomicAdd(&cnts[c * ND + sv.x], 1);
    atomicAdd(&cnts[c * ND + sv.y], 1);
    atomicAdd(&cnts[c * ND + sv.z], 1);
    atomicAdd(&cnts[c * ND + sv.w], 1);
    int4 rv;
    rv.x = atomicAdd(&cntd[c * NDIS + dv.x], 1);
    rv.y = atomicAdd(&cntd[c * NDIS + dv.y], 1);
    rv.z = atomicAdd(&cntd[c * NDIS + dv.z], 1);
    rv.w = atomicAdd(&cntd[c * NDIS + dv.w], 1);
    ((int4*)rank)[e4] = rv;
}

// ------- reduce copies: totals, in-place per-copy exclusive prefix, norm_out -------------
__global__ void k_red(int* __restrict__ cnts, int* __restrict__ cntd,
                      int* __restrict__ cnt_dst, float* __restrict__ norm_out) {
    int d = blockIdx.x * blockDim.x + threadIdx.x;
    if (d >= NDIS) return;
    int s = 0;
    #pragma unroll
    for (int c = 0; c < NCOPY; ++c) {
        int v = cntd[c * NDIS + d];
        cntd[c * NDIS + d] = s;       // overwrite with exclusive prefix (copyoff)
        s += v;
    }
    cnt_dst[d] = s;
    int s2 = 0;
    #pragma unroll
    for (int c = 0; c < NCOPY; ++c) s2 += cnts[c * ND + d];
    norm_out[d] = rsqrtf(fmaxf((float)s2, 1.f));
}

// ---------------- ELL fill, atomic-free: pos = (d<<7) + copyoff[c][d] + rank[e] ----------
__global__ void k_fill(const int* __restrict__ src, const int* __restrict__ dst,
                       const int* __restrict__ rank,
                       const int* __restrict__ copyoff, int* __restrict__ ell_src) {
    int e4 = blockIdx.x * blockDim.x + threadIdx.x;
    if (e4 >= E_EDGES / 4) return;
    int c = blockIdx.x & (NCOPY - 1);          // must match k_degrees' mapping
    int4 sv = ((const int4*)src)[e4];
    int4 dv = ((const int4*)dst)[e4];
    int4 rv = ((const int4*)rank)[e4];
    int ix = copyoff[c * NDIS + dv.x] + rv.x;
    int iy = copyoff[c * NDIS + dv.y] + rv.y;
    int iz = copyoff[c * NDIS + dv.z] + rv.z;
    int iw = copyoff[c * NDIS + dv.w] + rv.w;
    if (ix < ELLS) ell_src[(dv.x << 7) + ix] = sv.x;
    if (iy < ELLS) ell_src[(dv.y << 7) + iy] = sv.y;
    if (iz < ELLS) ell_src[(dv.z << 7) + iz] = sv.z;
    if (iw < ELLS) ell_src[(dv.w << 7) + iw] = sv.w;
}

// ===== FUSED aggregation + Z1 GEMM + weighted BN1 stats =====
// 512 thr = 8 waves. Phase A: wave w aggregates disease jb+w into LDS sA[w]
// (half-wave float4 gathers). Phase B: weight-stationary GEMM (M1 slice in regs).
__global__ __launch_bounds__(512) void k_aggz1(
        const int* __restrict__ ell_src, const int* __restrict__ cnt_dst,
        const float* __restrict__ norm_out, const float* __restrict__ h_drug,
        const float* __restrict__ M1, const float* __restrict__ c1,
        float* __restrict__ Z1, float* __restrict__ sum1, float* __restrict__ sumsq1) {
    __shared__ float sA[GJ][DIM];          // 4 KB
    __shared__ float sP[GJ][2][H1];        // 16 KB
    int tid = threadIdx.x;
    int k = tid & (H1 - 1);
    int isplit = tid >> 8;
    int wid = tid >> 6;                    // 0..7
    int lane = tid & 63;
    int half = lane >> 5, L = lane & 31;
    float m[64];
    #pragma unroll
    for (int r = 0; r < 64; ++r)
        m[r] = M1[(isplit * 64 + r) * H1 + k];
    float c1k = c1[k];
    float psum = 0.f, psq = 0.f;
    for (int grp = blockIdx.x; grp < NGRP; grp += gridDim.x) {
        int jb = grp * GJ;
        // ---- phase A: aggregate disease jb+wid into sA[wid] ----
        {
            int j = jb + wid;
            int n = cnt_dst[j];
            int nn = n < ELLS ? n : ELLS;
            int beg = j << 7;
            float4 acc = make_float4(0.f, 0.f, 0.f, 0.f);
            float4 acc2 = make_float4(0.f, 0.f, 0.f, 0.f);
            int i = half;
            for (; i + 2 < nn; i += 4) {   // two independent chains per half-wave
                int s0 = ell_src[beg + i];
                int s1 = ell_src[beg + i + 2];
                float n0 = norm_out[s0], n1 = norm_out[s1];
                float4 v0 = *(const float4*)&h_drug[(size_t)s0 * DIM + L * 4];
                float4 v1 = *(const float4*)&h_drug[(size_t)s1 * DIM + L * 4];
                acc.x += n0 * v0.x; acc.y += n0 * v0.y; acc.z += n0 * v0.z; acc.w += n0 * v0.w;
                acc2.x += n1 * v1.x; acc2.y += n1 * v1.y; acc2.z += n1 * v1.z; acc2.w += n1 * v1.w;
            }
            for (; i < nn; i += 2) {
                int s0 = ell_src[beg + i];
                float n0 = norm_out[s0];
                float4 v0 = *(const float4*)&h_drug[(size_t)s0 * DIM + L * 4];
                acc.x += n0 * v0.x; acc.y += n0 * v0.y; acc.z += n0 * v0.z; acc.w += n0 * v0.w;
            }
            acc.x += acc2.x; acc.y += acc2.y; acc.z += acc2.z; acc.w += acc2.w;
            acc.x += __shfl_down(acc.x, 32, 64);
            acc.y += __shfl_down(acc.y, 32, 64);
            acc.z += __shfl_down(acc.z, 32, 64);
            acc.w += __shfl_down(acc.w, 32, 64);
            if (half == 0) {
                float ni = rsqrtf(fmaxf((float)n, 1.f));
                sA[wid][L * 4 + 0] = acc.x * ni;
                sA[wid][L * 4 + 1] = acc.y * ni;
                sA[wid][L * 4 + 2] = acc.z * ni;
                sA[wid][L * 4 + 3] = acc.w * ni;
            }
        }
        __syncthreads();
        // ---- phase B: GEMM from sA ----
        #pragma unroll
        for (int g = 0; g < GJ; ++g) {
            const float4* a4 = (const float4*)sA[g] + isplit * 16;
            float p = 0.f;
            #pragma unroll
            for (int ii = 0; ii < 16; ++ii) {
                float4 v = a4[ii];   // wave-uniform address -> LDS broadcast
                p += v.x * m[4*ii] + v.y * m[4*ii+1] + v.z * m[4*ii+2] + v.w * m[4*ii+3];
            }
            sP[g][isplit][k] = p;
        }
        __syncthreads();
        if (tid < H1) {
            #pragma unroll
            for (int g = 0; g < GJ; ++g) {
                float z = sP[g][0][k] + sP[g][1][k] + c1k;
                Z1[(size_t)(jb + g) * H1 + k] = z;
                float w = (float)cnt_dst[jb + g];
                psum += w * z;
                psq  += w * z * z;
            }
        }
        __syncthreads();
    }
    if (tid < H1) {
        atomicAdd(&sum1[k], psum);
        atomicAdd(&sumsq1[k], psq);
    }
}

// ------- Z2 = relu(bn1(Z1)) @ W2 + b2 ; BN2 stats.  W2 column-slice in registers ---------
__global__ __launch_bounds__(512) void k_z2w(
        const float* __restrict__ Z1, const int* __restrict__ cnt_dst,
        const float* __restrict__ sum1, const float* __restrict__ sumsq1,
        const float* __restrict__ gamma1, const float* __restrict__ beta1,
        const float* __restrict__ W2, const float* __restrict__ b2,
        float* __restrict__ Z2, float* __restrict__ sum2, float* __restrict__ sumsq2) {
    __shared__ float sX[GJ][H1];           // 8 KB
    __shared__ float sP[GJ][4][H2];        // 16 KB
    __shared__ float sc1[H1], sh1[H1];     // 2 KB
    int tid = threadIdx.x;
    int k = tid & (H2 - 1);
    int csplit = tid >> 7;
    float w2r[64];
    #pragma unroll
    for (int r = 0; r < 64; ++r)
        w2r[r] = W2[(csplit * 64 + r) * H2 + k];
    if (tid < H1) {   // inline BN1 finalize
        float mn = sum1[tid] * (1.f / E_EDGES);
        float vv = sumsq1[tid] * (1.f / E_EDGES) - mn * mn;
        float s = rsqrtf(vv + EPSBN) * gamma1[tid];
        sc1[tid] = s;
        sh1[tid] = beta1[tid] - mn * s;
    }
    float b2k = b2[k];
    float psum = 0.f, psq = 0.f;
    __syncthreads();
    for (int grp = blockIdx.x; grp < NGRP; grp += gridDim.x) {
        int jb = grp * GJ;
        for (int x = tid; x < GJ * H1 / 4; x += 512) {
            float4 v = ((const float4*)(Z1 + (size_t)jb * H1))[x];
            int c = (x * 4) & (H1 - 1);
            v.x = fmaxf(v.x * sc1[c]     + sh1[c],     0.f);
            v.y = fmaxf(v.y * sc1[c + 1] + sh1[c + 1], 0.f);
            v.z = fmaxf(v.z * sc1[c + 2] + sh1[c + 2], 0.f);
            v.w = fmaxf(v.w * sc1[c + 3] + sh1[c + 3], 0.f);
            ((float4*)sX)[x] = v;
        }
        __syncthreads();
        #pragma unroll
        for (int g = 0; g < GJ; ++g) {
            const float4* x4 = (const float4*)sX[g] + csplit * 16;
            float p = 0.f;
            #pragma unroll
            for (int ii = 0; ii < 16; ++ii) {
                float4 v = x4[ii];   // wave-uniform address -> LDS broadcast
                p += v.x * w2r[4*ii] + v.y * w2r[4*ii+1] + v.z * w2r[4*ii+2] + v.w * w2r[4*ii+3];
            }
            sP[g][csplit][k] = p;
        }
        __syncthreads();
        if (tid < H2) {
            #pragma unroll
            for (int g = 0; g < GJ; ++g) {
                float z = sP[g][0][k] + sP[g][1][k] + sP[g][2][k] + sP[g][3][k] + b2k;
                Z2[(size_t)(jb + g) * H2 + k] = z;
                float w = (float)cnt_dst[jb + g];
                psum += w * z;
                psq  += w * z * z;
            }
        }
        __syncthreads();
    }
    if (tid < H2) {
        atomicAdd(&sum2[k], psum);
        atomicAdd(&sumsq2[k], psq);
    }
}

// ------- S[j] = sigmoid( relu(bn2(Z2[j])) @ W3 + b3 )  (BN2 hoisted, grid-stride) --------
__global__ void k_score(const float* __restrict__ Z2,
                        const float* __restrict__ sum2, const float* __restrict__ sumsq2,
                        const float* __restrict__ gamma2, const float* __restrict__ beta2,
                        const float* __restrict__ W3, const float* __restrict__ b3,
                        float* __restrict__ S) {
    int lane = threadIdx.x & 63;
    int gw = (blockIdx.x * blockDim.x + threadIdx.x) >> 6;
    int nw = (gridDim.x * blockDim.x) >> 6;
    // hoist per-column BN2 constants (cols lane and lane+64)
    int k0 = lane, k1 = lane + 64;
    float m0 = sum2[k0] * (1.f / E_EDGES);
    float v0 = sumsq2[k0] * (1.f / E_EDGES) - m0 * m0;
    float s0 = rsqrtf(v0 + EPSBN) * gamma2[k0];
    float h0 = beta2[k0] - m0 * s0;
    float w30 = W3[k0];
    float m1 = sum2[k1] * (1.f / E_EDGES);
    float v1 = sumsq2[k1] * (1.f / E_EDGES) - m1 * m1;
    float s1 = rsqrtf(v1 + EPSBN) * gamma2[k1];
    float h1 = beta2[k1] - m1 * s1;
    float w31 = W3[k1];
    float b3v = b3[0];
    for (int j = gw; j < NDIS; j += nw) {
        float x0 = fmaxf(Z2[(size_t)j * H2 + k0] * s0 + h0, 0.f) * w30;
        float x1 = fmaxf(Z2[(size_t)j * H2 + k1] * s1 + h1, 0.f) * w31;
        float acc = x0 + x1;
        for (int off = 32; off > 0; off >>= 1)
            acc += __shfl_down(acc, off, 64);
        if (lane == 0) S[j] = 1.f / (1.f + expf(-(acc + b3v)));
    }
}

// ---------------- out[e] = S[dst[e]]  (int4/float4) ----------------
__global__ void k_out(const int* __restrict__ dst, const float* __restrict__ S,
                      float* __restrict__ out) {
    int e4 = blockIdx.x * blockDim.x + threadIdx.x;
    if (e4 < E_EDGES / 4) {
        int4 d = ((const int4*)dst)[e4];
        float4 o;
        o.x = S[d.x]; o.y = S[d.y]; o.z = S[d.z]; o.w = S[d.w];
        ((float4*)out)[e4] = o;
    }
}

extern "C" void kernel_launch(void* const* d_in, const int* in_sizes, int n_in,
                              void* d_out, int out_size, void* d_ws, size_t ws_size,
                              hipStream_t stream) {
    const float* h_drug    = (const float*)d_in[0];
    // d_in[1] = d_disease: unused (diseases only receive; drugs' GCN output is b_gcn)
    const float* W_gcn     = (const float*)d_in[2];
    const float* b_gcn     = (const float*)d_in[3];
    const float* W1        = (const float*)d_in[4];
    const float* b1        = (const float*)d_in[5];
    const float* gamma1    = (const float*)d_in[6];
    const float* beta1     = (const float*)d_in[7];
    const float* W2        = (const float*)d_in[8];
    const float* b2        = (const float*)d_in[9];
    const float* gamma2    = (const float*)d_in[10];
    const float* beta2     = (const float*)d_in[11];
    const float* W3        = (const float*)d_in[12];
    const float* b3        = (const float*)d_in[13];
    const int*   src       = (const int*)d_in[14];
    const int*   dst       = (const int*)d_in[15];
    float* out = (float*)d_out;

    // ---- workspace: zero-region first (k_pre), then uninitialized scratch ----
    char* ws = (char*)d_ws;
    int*   cnts    = (int*)ws;                       // 32*ND
    int*   cntd    = cnts + NCOPY * ND;              // 32*NDIS (becomes copyoff)
    float* sum1    = (float*)(cntd + NCOPY * NDIS);  // 256
    float* sumsq1  = sum1 + H1;                      // 256
    float* sum2    = sumsq1 + H1;                    // 128
    float* sumsq2  = sum2 + H2;                      // 128
    float* zero_end = sumsq2 + H2;

    int*   cnt_dst  = (int*)zero_end;                // NDIS
    float* norm_out = (float*)(cnt_dst + NDIS);      // ND
    int*   rank     = (int*)(norm_out + ND);         // E
    int*   ell_src  = rank + E_EDGES;                // NDIS*ELLS
    float* M1       = (float*)(ell_src + NDIS * ELLS); // 128*256
    float* c1v      = M1 + DIM * H1;                 // 256
    float* Z1       = c1v + H1;                      // NDIS*256
    float* Z2       = Z1 + (size_t)NDIS * H1;        // NDIS*128
    float* S        = Z2 + (size_t)NDIS * H2;        // NDIS

    k_pre<<<ZBLK + DIM + 1, 256, 0, stream>>>((int4*)d_ws, W_gcn, W1, b_gcn, b1, M1, c1v);
    k_degrees<<<(E_EDGES / 4 + 255) / 256, 256, 0, stream>>>(src, dst, cnts, cntd, rank);
    k_red<<<(NDIS + 255) / 256, 256, 0, stream>>>(cnts, cntd, cnt_dst, norm_out);
    k_fill<<<(E_EDGES / 4 + 255) / 256, 256, 0, stream>>>(src, dst, rank, cntd, ell_src);
    k_aggz1<<<WSGRID, 512, 0, stream>>>(ell_src, cnt_dst, norm_out, h_drug, M1, c1v,
                                        Z1, sum1, sumsq1);
    k_z2w<<<WSGRID, 512, 0, stream>>>(Z1, cnt_dst, sum1, sumsq1, gamma1, beta1,
                                      W2, b2, Z2, sum2, sumsq2);
    k_score<<<512, 256, 0, stream>>>(Z2, sum2, sumsq2, gamma2, beta2, W3, b3, S);
    k_out<<<(E_EDGES / 4 + 255) / 256, 256, 0, stream>>>(dst, S, out);
}